// Round 1
// baseline (1135.409 us; speedup 1.0000x reference)
//
#include <hip/hip_runtime.h>
#include <hip/hip_bf16.h>
#include <stdint.h>

#define M_ROWS 300000
#define NPTS   600000

typedef __attribute__((ext_vector_type(8)))  short bf16x8;
typedef __attribute__((ext_vector_type(16))) float f32x16;

union U4 { uint4 u; bf16x8 h; unsigned short us[8]; };

__device__ __forceinline__ unsigned short f2bf(float f) {
  union { float f; uint32_t u; } v; v.f = f;
  uint32_t r = v.u + 0x7fffu + ((v.u >> 16) & 1u);
  return (unsigned short)(r >> 16);
}

// ---- packed weight tile table (tiles of 32 cols x 16 k, 1 KiB each) ----
#define T_SP 0
#define T_ST 64
#define T_P1 128
#define T_P2 256
#define T_R1 272
#define T_R2 400
#define T_S1 416
#define T_S2 544
#define T_W1 576
#define T_W2 704
#define T_M1 720
#define T_M2 848
#define T_TOT 864

__global__ void prep_w(const float* Wsp, const float* Wst, const float* Wp1, const float* Wp2,
                       const float* Wr1, const float* Wr2, const float* Ws1, const float* Ws2,
                       const float* Ww1, const float* Ww2, const float* Wm1, const float* Wm2,
                       uint4* ws) {
  int b = blockIdx.x, l = threadIdx.x;
  const int starts[12] = {T_SP,T_ST,T_P1,T_P2,T_R1,T_R2,T_S1,T_S2,T_W1,T_W2,T_M1,T_M2};
  const int Ks[12]     = {128,128,256,256,256,256,256,256,256,256,256,256};
  const int Cos[12]    = {256,256,256,9,256,4,256,48,256,1,256,1};
  const float* Wp[12]  = {Wsp,Wst,Wp1,Wp2,Wr1,Wr2,Ws1,Ws2,Ww1,Ww2,Wm1,Wm2};
  int m = 0;
  #pragma unroll
  for (int i = 1; i < 12; ++i) if (b >= starts[i]) m = i;
  int local = b - starts[m];
  int KT = Ks[m] >> 4;
  int n0 = local / KT, k0 = local - n0 * KT;
  int col = n0 * 32 + (l & 31);
  int kbase = k0 * 16 + (l >> 5) * 8;
  const float* W = Wp[m];
  int Co = Cos[m];
  U4 pk;
  #pragma unroll
  for (int j = 0; j < 8; ++j) {
    float v = (col < Co) ? W[(size_t)(kbase + j) * Co + col] : 0.0f;
    pk.us[j] = f2bf(v);
  }
  ws[(size_t)b * 64 + l] = pk.u;
}

// ---- bulk copy of embeddings into output (non-indexed rows) ----
__global__ void copy_emb(const float4* pts, const float4* rot, const float4* h,
                         const float4* shs, float4* out) {
  long long stride = (long long)gridDim.x * blockDim.x;
  for (long long i = (long long)blockIdx.x * blockDim.x + threadIdx.x; i < 8400000LL; i += stride) {
    float4 v;
    if (i < 450000)        v = pts[i];
    else if (i < 1050000)  v = rot[i - 450000];
    else if (i < 1200000)  v = h[i - 1050000];
    else                   v = shs[i - 1200000];
    out[i] = v;
  }
}

// ---- fused MLP kernel ----
#define LSTR 512
__device__ __forceinline__ int lds_addr(int row, int cb) {
  return row * LSTR + (cb ^ ((row & 15) << 4));
}

__device__ __forceinline__ void loadX(const float* grid, int row0, int t, char* buf) {
  #pragma unroll
  for (int i = 0; i < 8; ++i) {
    int fi = i * 256 + t;
    int row = fi >> 5;
    int c4 = fi & 31;
    int gr = row0 + row; gr = gr < M_ROWS ? gr : (M_ROWS - 1);
    float4 v = ((const float4*)grid)[(size_t)gr * 32 + c4];
    ushort4 p;
    p.x = f2bf(v.x); p.y = f2bf(v.y); p.z = f2bf(v.z); p.w = f2bf(v.w);
    *(ushort4*)(buf + lds_addr(row, c4 * 8)) = p;
  }
}

template<int KT>
__device__ __forceinline__ void big_layer(const uint4* wt, const float* bias,
                                          const char* inb, char* outb,
                                          int wave, int lane) {
  f32x16 acc[2][2];
  #pragma unroll
  for (int n = 0; n < 2; ++n)
    #pragma unroll
    for (int r = 0; r < 2; ++r)
      acc[n][r] = (f32x16)0.0f;
  const int arow0 = lane & 31;
  const int khalf = (lane >> 5) * 16;
  #pragma unroll
  for (int kc = 0; kc < KT / 8; ++kc) {
    bf16x8 a[2][8];
    #pragma unroll
    for (int r = 0; r < 2; ++r)
      #pragma unroll
      for (int k8 = 0; k8 < 8; ++k8) {
        int row = r * 32 + arow0;
        int cb = (kc * 8 + k8) * 32 + khalf;
        a[r][k8] = *(const bf16x8*)(inb + lds_addr(row, cb));
      }
    #pragma unroll
    for (int n = 0; n < 2; ++n) {
      const int n0 = wave * 2 + n;
      #pragma unroll
      for (int k8 = 0; k8 < 8; ++k8) {
        U4 b; b.u = wt[(size_t)((n0 * KT + kc * 8 + k8) * 64 + lane)];
        acc[n][0] = __builtin_amdgcn_mfma_f32_32x32x16_bf16(a[0][k8], b.h, acc[n][0], 0, 0, 0);
        acc[n][1] = __builtin_amdgcn_mfma_f32_32x32x16_bf16(a[1][k8], b.h, acc[n][1], 0, 0, 0);
      }
    }
  }
  #pragma unroll
  for (int n = 0; n < 2; ++n) {
    int col = (wave * 2 + n) * 32 + (lane & 31);
    float bv = bias[col];
    #pragma unroll
    for (int r = 0; r < 2; ++r)
      #pragma unroll
      for (int q = 0; q < 16; ++q) {
        int row = r * 32 + (q & 3) + 8 * (q >> 2) + 4 * (lane >> 5);
        float v = acc[n][r][q] + bv;
        v = v > 0.0f ? v : 0.0f;
        *(unsigned short*)(outb + lds_addr(row, col * 2)) = f2bf(v);
      }
  }
}

template<int NT, int COLS>
__device__ __forceinline__ void small_layer(const uint4* wt, const char* inb,
                                            float* outsm, int wave, int lane) {
  f32x16 acc[NT][2];
  #pragma unroll
  for (int n = 0; n < NT; ++n) { acc[n][0] = (f32x16)0.0f; acc[n][1] = (f32x16)0.0f; }
  const int arow0 = lane & 31;
  const int khalf = (lane >> 5) * 16;
  #pragma unroll
  for (int k4 = 0; k4 < 4; ++k4) {
    int k = wave * 4 + k4;
    bf16x8 a0 = *(const bf16x8*)(inb + lds_addr(arow0, k * 32 + khalf));
    bf16x8 a1 = *(const bf16x8*)(inb + lds_addr(32 + arow0, k * 32 + khalf));
    #pragma unroll
    for (int n = 0; n < NT; ++n) {
      U4 b; b.u = wt[(size_t)((n * 16 + k) * 64 + lane)];
      acc[n][0] = __builtin_amdgcn_mfma_f32_32x32x16_bf16(a0, b.h, acc[n][0], 0, 0, 0);
      acc[n][1] = __builtin_amdgcn_mfma_f32_32x32x16_bf16(a1, b.h, acc[n][1], 0, 0, 0);
    }
  }
  #pragma unroll
  for (int n = 0; n < NT; ++n) {
    int col = n * 32 + (lane & 31);
    if (col < COLS) {
      #pragma unroll
      for (int r = 0; r < 2; ++r)
        #pragma unroll
        for (int q = 0; q < 16; ++q) {
          int row = r * 32 + (q & 3) + 8 * (q >> 2) + 4 * (lane >> 5);
          atomicAdd(&outsm[row * COLS + col], acc[n][r][q]);
        }
    }
  }
}

__global__ void __launch_bounds__(256, 2) deform_main(
    const float* grid_sp, const float* grid_st, const int* idx,
    const float* rays, const float* rotq, const float* shs_in,
    const float* time_emb, const float* h_emb,
    const uint4* ws,
    const float* b_sp, const float* b_st, const float* b_p1, const float* b_p2,
    const float* b_r1, const float* b_r2, const float* b_s1, const float* b_s2,
    const float* b_w1, const float* b_w2, const float* b_m1, const float* b_m2,
    float* out) {
  __shared__ uint4 ldsu[4960];   // 79360 B: bufA 32K | bufB 32K | small 13.5K
  char* bufA = (char*)ldsu;
  char* bufB = bufA + 32768;
  float* sm   = (float*)(bufA + 65536);
  float* dxb  = sm;          // [64*9]  (aliases shsb, disjoint in time)
  float* shsb = sm;          // [64*48]
  float* wb   = sm + 3072;   // [64]
  float* mub  = sm + 3136;   // [64]
  float* rotb = sm + 3200;   // [64*4]

  const int t = threadIdx.x;
  const int lane = t & 63;
  const int wave = t >> 6;
  const int row0 = blockIdx.x * 64;

  // P0: zero small accumulators, stage X_sp
  for (int i = t; i < 576; i += 256) dxb[i] = 0.0f;
  for (int i = 3072 + t; i < 3456; i += 256) sm[i] = 0.0f;
  loadX(grid_sp, row0, t, bufA);
  __syncthreads();
  // P1: hsp = relu(X@Wsp + b)
  big_layer<8>(ws + T_SP * 64, b_sp, bufA, bufB, wave, lane);
  __syncthreads();
  // P2: hp = relu(hsp@Wp1 + b)
  big_layer<16>(ws + T_P1 * 64, b_p1, bufB, bufA, wave, lane);
  __syncthreads();
  // P3: dx_raw = hp@Wp2
  small_layer<1, 9>(ws + T_P2 * 64, bufA, dxb, wave, lane);
  __syncthreads();
  // P4: hw
  big_layer<16>(ws + T_W1 * 64, b_w1, bufB, bufA, wave, lane);
  __syncthreads();
  // P5: w_raw
  small_layer<1, 1>(ws + T_W2 * 64, bufA, wb, wave, lane);
  __syncthreads();
  // P6: hm
  big_layer<16>(ws + T_M1 * 64, b_m1, bufB, bufA, wave, lane);
  __syncthreads();
  // P7: mu_raw
  small_layer<1, 1>(ws + T_M2 * 64, bufA, mub, wave, lane);
  __syncthreads();
  // P8+P9: sp-path epilogue (pts, opacity) + stage X_st
  loadX(grid_st, row0, t, bufA);
  {
    int row = t >> 2, sub = t & 3;
    int gr = row0 + row;
    if (gr < M_ROWS) {
      int g = idx[gr];
      float tt = time_emb[0];
      if (sub < 3) {
        float mt = 1.0f - tt;
        float c0 = 3.0f * mt * mt * tt, c1 = 3.0f * mt * tt * tt, c2 = tt * tt * tt;
        float d0 = dxb[row * 9 + sub]     + b_p2[sub];
        float d1 = dxb[row * 9 + 3 + sub] + b_p2[3 + sub];
        float d2 = dxb[row * 9 + 6 + sub] + b_p2[6 + sub];
        out[(size_t)g * 3 + sub] = rays[(size_t)g * 3 + sub] + (c0 * d0 + c1 * d1 + c2 * d2);
      } else {
        float wr = wb[row] + b_w2[0];
        float mr = mub[row] + b_m2[0];
        float mu = 1.0f / (1.0f + expf(-mr));
        float dtm = tt - mu;
        out[4200000 + (size_t)g] = h_emb[g] * expf(-(wr * wr) * dtm * dtm);
      }
    }
  }
  __syncthreads();
  // P10: hst = relu(X@Wst + b)
  big_layer<8>(ws + T_ST * 64, b_st, bufA, bufB, wave, lane);
  __syncthreads();
  // P11: hr
  big_layer<16>(ws + T_R1 * 64, b_r1, bufB, bufA, wave, lane);
  __syncthreads();
  // P12: rot_raw (+ zero shs accumulator, aliases dead dxb)
  for (int i = t; i < 3072; i += 256) shsb[i] = 0.0f;
  small_layer<1, 4>(ws + T_R2 * 64, bufA, rotb, wave, lane);
  __syncthreads();
  // P13: rot epilogue
  {
    int row = t >> 2, c = t & 3;
    int gr = row0 + row;
    if (gr < M_ROWS) {
      int g = idx[gr];
      out[1800000 + (size_t)g * 4 + c] = rotq[(size_t)g * 4 + c] + rotb[row * 4 + c] + b_r2[c];
    }
  }
  __syncthreads();
  // P14: hs
  big_layer<16>(ws + T_S1 * 64, b_s1, bufB, bufA, wave, lane);
  __syncthreads();
  // P15: shs_raw
  small_layer<2, 48>(ws + T_S2 * 64, bufA, shsb, wave, lane);
  __syncthreads();
  // P16: shs epilogue
  #pragma unroll
  for (int i = 0; i < 12; ++i) {
    int e = i * 256 + t;
    int row = e / 48;
    int c = e - row * 48;
    int gr = row0 + row;
    if (gr < M_ROWS) {
      int g = idx[gr];
      out[4800000 + (size_t)g * 48 + c] = shs_in[(size_t)g * 48 + c] + shsb[e] + b_s2[c];
    }
  }
}

extern "C" void kernel_launch(void* const* d_in, const int* in_sizes, int n_in,
                              void* d_out, int out_size, void* d_ws, size_t ws_size,
                              hipStream_t stream) {
  const float* rays     = (const float*)d_in[0];
  const float* rotq     = (const float*)d_in[1];
  const float* shs      = (const float*)d_in[2];
  const float* time_emb = (const float*)d_in[3];
  const float* h_emb    = (const float*)d_in[4];
  const float* grid_sp  = (const float*)d_in[5];
  const float* grid_st  = (const float*)d_in[6];
  const int*   idx      = (const int*)d_in[7];
  uint4* ws = (uint4*)d_ws;

  prep_w<<<T_TOT, 64, 0, stream>>>(
      (const float*)d_in[8],  (const float*)d_in[10], (const float*)d_in[12], (const float*)d_in[14],
      (const float*)d_in[16], (const float*)d_in[18], (const float*)d_in[20], (const float*)d_in[22],
      (const float*)d_in[24], (const float*)d_in[26], (const float*)d_in[28], (const float*)d_in[30],
      ws);

  copy_emb<<<2048, 256, 0, stream>>>((const float4*)rays, (const float4*)rotq,
                                     (const float4*)h_emb, (const float4*)shs, (float4*)d_out);

  deform_main<<<(M_ROWS + 63) / 64, 256, 0, stream>>>(
      grid_sp, grid_st, idx, rays, rotq, shs, time_emb, h_emb, ws,
      (const float*)d_in[9],  (const float*)d_in[11], (const float*)d_in[13], (const float*)d_in[15],
      (const float*)d_in[17], (const float*)d_in[19], (const float*)d_in[21], (const float*)d_in[23],
      (const float*)d_in[25], (const float*)d_in[27], (const float*)d_in[29], (const float*)d_in[31],
      (float*)d_out);
}